// Round 17
// baseline (161.487 us; speedup 1.0000x reference)
//
#include <hip/hip_runtime.h>
#include <cstdint>
#include <cstddef>

#define J 64
#define XD 512
#define HD 1024
#define YD 16
#define PP 8
#define NN 1024

typedef __bf16 bf16;
typedef __attribute__((ext_vector_type(8))) __bf16 bf16x8;
typedef __attribute__((ext_vector_type(4))) __bf16 bf16x4;
typedef __attribute__((ext_vector_type(4))) float f32x4;

__device__ __forceinline__ void gload16(const void* g, void* l) {
  __builtin_amdgcn_global_load_lds((__attribute__((address_space(1))) void*)(g),
                                   (__attribute__((address_space(3))) void*)(l),
                                   16, 0, 0);
}

// ---- K1 (merged): blocks [0,8192) build W1T; blocks [8192,14596) build the rest.
__global__ __launch_bounds__(256) void build_all(
    const float* __restrict__ muW1, const float* __restrict__ sigW1,
    const float* __restrict__ eW1, bf16* __restrict__ W1T,
    const float* __restrict__ x,
    const float* __restrict__ muW2, const float* __restrict__ sigW2,
    const float* __restrict__ eW2,
    const float* __restrict__ mub1, const float* __restrict__ sigb1,
    const float* __restrict__ eb1,
    const float* __restrict__ mub2, const float* __restrict__ sigb2,
    const float* __restrict__ eb2,
    bf16* __restrict__ XBF, bf16* __restrict__ W2T,
    float* __restrict__ B1W, float* __restrict__ B2W) {
  __shared__ bf16 sT[64][66];  // used only by the W1T path
  int b = blockIdx.x;
  int tid = threadIdx.x;
  if (b < 8192) {
    int j = b >> 7;
    int xt = (b >> 4) & 7;
    int ht = b & 15;
    int x0 = xt << 6, h0 = ht << 6;
    int rp = tid >> 4;
    int cp = (tid & 15) << 2;
    const float* eB = eW1 + (size_t)j * (XD * HD);
#pragma unroll
    for (int p = 0; p < 4; ++p) {
      int xx = rp + (p << 4);
      size_t gi = (size_t)(x0 + xx) * HD + (h0 + cp);
      f32x4 e = *(const f32x4*)(eB + gi);
      f32x4 m = *(const f32x4*)(muW1 + gi);
      f32x4 s = *(const f32x4*)(sigW1 + gi);
#pragma unroll
      for (int i = 0; i < 4; ++i) sT[cp + i][xx] = (bf16)(m[i] + e[i] * s[i]);
    }
    __syncthreads();
#pragma unroll
    for (int p = 0; p < 4; ++p) {
      int h = rp + (p << 4);
      bf16x4 v;
#pragma unroll
      for (int i = 0; i < 4; ++i) v[i] = sT[h][cp + i];
      *(bf16x4*)(W1T + (size_t)(j * HD + h0 + h) * XD + (x0 + cp)) = v;
    }
    return;
  }
  int i = (b - 8192) * 256 + tid;
  const int c0 = NN * XD;
  const int c1 = J * YD * HD;
  const int c2 = J * HD;
  const int c3 = J * YD;
  if (i < c0) { XBF[i] = (bf16)x[i]; return; }
  i -= c0;
  if (i < c1) {
    int h = i & (HD - 1);
    int jy = i >> 10;
    int y = jy & 15;
    int j = jy >> 4;
    float mu = muW2[h * YD + y], sg = sigW2[h * YD + y];
    float e = eW2[((size_t)j * HD + h) * YD + y];
    W2T[i] = (bf16)(mu + e * sg);
    return;
  }
  i -= c1;
  if (i < c2) {
    int h = i & (HD - 1);
    B1W[i] = mub1[h] + eb1[i] * sigb1[h];
    return;
  }
  i -= c2;
  if (i < c3) {
    int y = i & 15;
    B2W[i] = mub2[y] + eb2[i] * sigb2[y];
  }
}

// ---- K2: fused GEMM1 + clip + GEMM2 + permutation scatter
// grid 512 (64 j x 8 n-tiles of 128), 256 threads / 4 waves (2n x 2h),
// block tile 128n x 128h per hb (8 hb), wave tile 64x64, acc1[4][4]=64 f32
// -> VGPR ~100 (R6-measured at this acc count) -> 2 waves/SIMD needs only
// ~224/512 regs. LDS = 64KB EXACTLY -> 2 blocks/CU: independent-block overlap
// fills the per-step vmcnt/barrier bubbles (R16's attempt failed only because
// VGPR 244 x 2 = the whole file; this point is register-safe).
// sH [128n][128h] 32KB OVERLAPS the sA dbuf region (dead between K-loops);
// each hb boundary does one cold re-stage (overlapped by the co-resident block).
// LDS: sA dbuf 2x16KB @0 (= sH region), sB dbuf 2x16KB @32768. Total 65536.
__global__ __launch_bounds__(256)
void fused_mlp(
    const bf16* __restrict__ XBF, const bf16* __restrict__ W1T,
    const bf16* __restrict__ W2T, const float* __restrict__ B1W,
    const float* __restrict__ B2W, const float* __restrict__ permu,
    float* __restrict__ out) {
  extern __shared__ char smem[];          // 65536 bytes

  int bid = blockIdx.x;
  // XCD swizzle: XCD x gets j in [8x,8x+8), all 8 n-tiles of each j together
  int L = ((bid & 7) << 6) | (bid >> 3);
  int j = L >> 3;
  int n0 = (L & 7) << 7;

  int tid = threadIdx.x;
  int wid = tid >> 6;               // 0..3
  int lane = tid & 63;
  int l15 = lane & 15;
  int lg = lane >> 4;               // 0..3
  int wn = (wid >> 1) << 6;         // wave n offset (0,64)
  int wh = (wid & 1) << 6;          // wave h offset (0,64)

  const bf16* w1base = W1T + (size_t)j * (HD * XD);
  const bf16* w2g = W2T + (size_t)((j << 4) + l15) * HD;  // row y = l15
  bf16* sH = (bf16*)smem;           // overlaps sA dbuf

  f32x4 acc2[2];
#pragma unroll
  for (int f = 0; f < 2; ++f)
#pragma unroll
    for (int r = 0; r < 4; ++r) acc2[f][r] = 0.0f;

  // stage into buf d: sA = x rows [n0,n0+128) @0, sB = W1T rows [hb*128,+128) @32K
  // rows of 128B, slot s phys: src col = (s ^ (r&7))*8 elems (R9/R15 swizzle)
  auto stage = [&](int d, int k0, int hb_) {
#pragma unroll
    for (int q = 0; q < 4; ++q) {
      int r = (q << 5) + (tid >> 3);
      int sc = (tid & 7) ^ (r & 7);
      int doff = (q << 12) + (tid << 4);
      gload16(XBF + (size_t)(n0 + r) * XD + k0 + (sc << 3),
              smem + d * 16384 + doff);
      gload16(w1base + (size_t)((hb_ << 7) + r) * XD + k0 + (sc << 3),
              smem + 32768 + d * 16384 + doff);
    }
  };

  // prologue
  stage(0, 0, 0);
  asm volatile("s_waitcnt vmcnt(0)" ::: "memory");
  __builtin_amdgcn_s_barrier();

#pragma unroll 1
  for (int hb = 0; hb < 8; ++hb) {
    // acc1[fb][fa]: fb = W1T(h) fragment, fa = x(n) fragment (swapped-operand)
    f32x4 acc1[4][4];
#pragma unroll
    for (int fb = 0; fb < 4; ++fb)
#pragma unroll
      for (int fa = 0; fa < 4; ++fa)
#pragma unroll
        for (int r = 0; r < 4; ++r) acc1[fb][fa][r] = 0.0f;

#pragma unroll 1
    for (int t = 0; t < 8; ++t) {
      int cur = t & 1;
      const char* a_d = smem + cur * 16384;
      const char* b_d = smem + 32768 + cur * 16384;
#pragma unroll
      for (int kk = 0; kk < 2; ++kk) {
        bf16x8 af[4], bg[4];
#pragma unroll
        for (int fa = 0; fa < 4; ++fa) {
          int ra = wn + (fa << 4) + l15;
          int ca = ((kk << 6) + (lg << 4)) ^ ((ra & 7) << 4);
          af[fa] = *(const bf16x8*)(a_d + (ra << 7) + ca);
        }
#pragma unroll
        for (int fb = 0; fb < 4; ++fb) {
          int rb = wh + (fb << 4) + l15;
          int cb = ((kk << 6) + (lg << 4)) ^ ((rb & 7) << 4);
          bg[fb] = *(const bf16x8*)(b_d + (rb << 7) + cb);
        }
        // stage issue after the first read burst (R15-proven order);
        // t==7 has no prefetch: the sA region becomes sH next.
        if (kk == 0 && t < 7) stage(cur ^ 1, (t + 1) << 6, hb);
        __builtin_amdgcn_s_setprio(1);
#pragma unroll
        for (int fb = 0; fb < 4; ++fb)
#pragma unroll
          for (int fa = 0; fa < 4; ++fa)
            acc1[fb][fa] = __builtin_amdgcn_mfma_f32_16x16x32_bf16(
                bg[fb], af[fa], acc1[fb][fa], 0, 0, 0);   // A=W1(h), B=x(n)
        __builtin_amdgcn_s_setprio(0);
      }
      asm volatile("s_waitcnt vmcnt(0)" ::: "memory");
      __builtin_amdgcn_s_barrier();
    }

    // W2 fragments for this hb (latency hidden under the sH-write phase)
    bf16x8 wg[4];
#pragma unroll
    for (int kk2 = 0; kk2 < 4; ++kk2)
      wg[kk2] = *(const bf16x8*)(w2g + (hb << 7) + (kk2 << 5) + (lg << 3));

    // ---- b1 + hardtanh -> sH [128n][128h] (over the dead sA region)
    f32x4 b1v[4];
#pragma unroll
    for (int fb = 0; fb < 4; ++fb)
      b1v[fb] = *(const f32x4*)&B1W[(j << 10) + (hb << 7) + wh + (fb << 4) + (lg << 2)];
#pragma unroll
    for (int fa = 0; fa < 4; ++fa) {
#pragma unroll
      for (int fb = 0; fb < 4; ++fb) {
        bf16x4 pk;
#pragma unroll
        for (int r = 0; r < 4; ++r) {
          float v = acc1[fb][fa][r] + b1v[fb][r];
          v = fminf(1.0f, fmaxf(-1.0f, v));
          pk[r] = (bf16)v;
        }
        int n = wn + (fa << 4) + l15;
        int colb = (wh + (fb << 4) + (lg << 2)) << 1;   // byte col, 8B aligned
        int byte = (n << 8) + (colb ^ ((n & 7) << 4));
        *(bf16x4*)((char*)sH + byte) = pk;
      }
    }
    asm volatile("s_waitcnt lgkmcnt(0)" ::: "memory");
    __builtin_amdgcn_s_barrier();   // sH visible
    // ---- GEMM2: wave owns rows wid*32..+32 of 128
#pragma unroll
    for (int kk2 = 0; kk2 < 4; ++kk2) {
#pragma unroll
      for (int f = 0; f < 2; ++f) {
        int row = (wid << 5) + (f << 4) + l15;
        int cb = ((kk2 << 6) + (lg << 4)) ^ ((row & 7) << 4);
        bf16x8 hf = *(const bf16x8*)((char*)sH + (row << 8) + cb);
        acc2[f] = __builtin_amdgcn_mfma_f32_16x16x32_bf16(hf, wg[kk2], acc2[f], 0, 0, 0);
      }
    }
    if (hb < 7) {
      __builtin_amdgcn_s_barrier();   // all GEMM2 reads of sH done
      stage(0, 0, hb + 1);            // cold stage into buf0 (over sH: safe now)
      asm volatile("s_waitcnt vmcnt(0)" ::: "memory");
      __builtin_amdgcn_s_barrier();
    }
  }

  // ---- epilogue: b2, out tile via LDS (over sH region — barrier first)
  __syncthreads();
  float b2v = B2W[(j << 4) + l15];
  float* sOut = (float*)smem;              // [128][17] f32 = 8704B
  int* sIdx = (int*)(smem + 12288);        // [128]
#pragma unroll
  for (int f = 0; f < 2; ++f)
#pragma unroll
    for (int r = 0; r < 4; ++r) {
      int row = (wid << 5) + (f << 4) + (lg << 2) + r;
      sOut[row * 17 + l15] = acc2[f][r] + b2v;
    }
  if (tid < 128) {  // cidx[p][y] = col c with permu[p][c][y]==1
    int p = tid >> 4, y = tid & 15;
    int c = 0;
#pragma unroll
    for (int cc = 0; cc < 16; ++cc)
      if (permu[((p << 4) + cc) * 16 + y] > 0.5f) c = cc;
    sIdx[tid] = c;
  }
  __syncthreads();
#pragma unroll 1
  for (int it = 0; it < 16; ++it) {
    int flat = (it << 10) + (tid << 2);   // p[3] n[7] y[4]
    int p = flat >> 11;
    int n = (flat >> 4) & 127;
    int y0 = flat & 15;
    f32x4 v;
#pragma unroll
    for (int q = 0; q < 4; ++q) v[q] = sOut[n * 17 + sIdx[(p << 4) + y0 + q]];
    *(f32x4*)(out + ((size_t)((j << 3) + p) * NN + n0 + n) * YD + y0) = v;
  }
}

extern "C" void kernel_launch(void* const* d_in, const int* in_sizes, int n_in,
                              void* d_out, int out_size, void* d_ws, size_t ws_size,
                              hipStream_t stream) {
  (void)in_sizes; (void)n_in; (void)out_size; (void)ws_size;
  const float* x      = (const float*)d_in[0];
  const float* mu_W1  = (const float*)d_in[1];
  const float* mu_b1  = (const float*)d_in[2];
  const float* mu_W2  = (const float*)d_in[3];
  const float* mu_b2  = (const float*)d_in[4];
  const float* sig_W1 = (const float*)d_in[5];
  const float* sig_b1 = (const float*)d_in[6];
  const float* sig_W2 = (const float*)d_in[7];
  const float* sig_b2 = (const float*)d_in[8];
  const float* e_W1   = (const float*)d_in[9];
  const float* e_b1   = (const float*)d_in[10];
  const float* e_W2   = (const float*)d_in[11];
  const float* e_b2   = (const float*)d_in[12];
  const float* permu  = (const float*)d_in[13];
  float* out = (float*)d_out;

  char* ws = (char*)d_ws;
  bf16* W1T = (bf16*)(ws);
  bf16* W2T = (bf16*)(ws + 67108864);
  bf16* XBF = (bf16*)(ws + 69206016);
  float* B1W = (float*)(ws + 70254592);
  float* B2W = (float*)(ws + 70516736);

  build_all<<<dim3(14596), dim3(256), 0, stream>>>(
      mu_W1, sig_W1, e_W1, W1T,
      x, mu_W2, sig_W2, e_W2, mu_b1, sig_b1, e_b1, mu_b2, sig_b2, e_b2,
      XBF, W2T, B1W, B2W);
  fused_mlp<<<dim3(512), dim3(256), 65536, stream>>>(
      XBF, W1T, W2T, B1W, B2W, permu, out);
}

// Round 18
// 119.184 us; speedup vs baseline: 1.3549x; 1.3549x over previous
//
#include <hip/hip_runtime.h>
#include <cstdint>
#include <cstddef>

#define J 64
#define XD 512
#define HD 1024
#define YD 16
#define PP 8
#define NN 1024

typedef __bf16 bf16;
typedef __attribute__((ext_vector_type(8))) __bf16 bf16x8;
typedef __attribute__((ext_vector_type(4))) __bf16 bf16x4;
typedef __attribute__((ext_vector_type(4))) float f32x4;

__device__ __forceinline__ void gload16(const void* g, void* l) {
  __builtin_amdgcn_global_load_lds((__attribute__((address_space(1))) void*)(g),
                                   (__attribute__((address_space(3))) void*)(l),
                                   16, 0, 0);
}

// ---- K1 (merged): blocks [0,8192) build W1T; blocks [8192,14596) build the rest.
__global__ __launch_bounds__(256) void build_all(
    const float* __restrict__ muW1, const float* __restrict__ sigW1,
    const float* __restrict__ eW1, bf16* __restrict__ W1T,
    const float* __restrict__ x,
    const float* __restrict__ muW2, const float* __restrict__ sigW2,
    const float* __restrict__ eW2,
    const float* __restrict__ mub1, const float* __restrict__ sigb1,
    const float* __restrict__ eb1,
    const float* __restrict__ mub2, const float* __restrict__ sigb2,
    const float* __restrict__ eb2,
    bf16* __restrict__ XBF, bf16* __restrict__ W2T,
    float* __restrict__ B1W, float* __restrict__ B2W) {
  __shared__ bf16 sT[64][66];  // used only by the W1T path
  int b = blockIdx.x;
  int tid = threadIdx.x;
  if (b < 8192) {
    // W1T[j][h][x] = bf16(mu_W1[x][h] + e_W1[j][x][h]*sig_W1[x][h])
    int j = b >> 7;
    int xt = (b >> 4) & 7;
    int ht = b & 15;
    int x0 = xt << 6, h0 = ht << 6;
    int rp = tid >> 4;
    int cp = (tid & 15) << 2;
    const float* eB = eW1 + (size_t)j * (XD * HD);
#pragma unroll
    for (int p = 0; p < 4; ++p) {
      int xx = rp + (p << 4);
      size_t gi = (size_t)(x0 + xx) * HD + (h0 + cp);
      f32x4 e = *(const f32x4*)(eB + gi);
      f32x4 m = *(const f32x4*)(muW1 + gi);
      f32x4 s = *(const f32x4*)(sigW1 + gi);
#pragma unroll
      for (int i = 0; i < 4; ++i) sT[cp + i][xx] = (bf16)(m[i] + e[i] * s[i]);
    }
    __syncthreads();
#pragma unroll
    for (int p = 0; p < 4; ++p) {
      int h = rp + (p << 4);
      bf16x4 v;
#pragma unroll
      for (int i = 0; i < 4; ++i) v[i] = sT[h][cp + i];
      *(bf16x4*)(W1T + (size_t)(j * HD + h0 + h) * XD + (x0 + cp)) = v;
    }
    return;
  }
  int i = (b - 8192) * 256 + tid;
  const int c0 = NN * XD;        // 524288
  const int c1 = J * YD * HD;    // 1048576
  const int c2 = J * HD;         // 65536
  const int c3 = J * YD;         // 1024
  if (i < c0) { XBF[i] = (bf16)x[i]; return; }
  i -= c0;
  if (i < c1) {
    int h = i & (HD - 1);
    int jy = i >> 10;
    int y = jy & 15;
    int j = jy >> 4;
    float mu = muW2[h * YD + y], sg = sigW2[h * YD + y];
    float e = eW2[((size_t)j * HD + h) * YD + y];
    W2T[i] = (bf16)(mu + e * sg);
    return;
  }
  i -= c1;
  if (i < c2) {
    int h = i & (HD - 1);
    B1W[i] = mub1[h] + eb1[i] * sigb1[h];
    return;
  }
  i -= c2;
  if (i < c3) {
    int y = i & 15;
    B2W[i] = mub2[y] + eb2[i] * sigb2[y];
  }
}

// ---- K2: fused GEMM1 + clip + GEMM2 + permutation scatter
// CHAMPION CONFIG (R15, 119.3us total / 91.6us fused; session conclusion):
// R9 geometry/schedule: 8 waves (4n x 2h), wave tile 64x64, BM=256 BN=128 BK=64,
// swapped-operand GEMM1 (packed bf16x4 sH writes), W2-frag hoist, setprio,
// stage issued after kk=0's frag reads (reads own the LDS pipe post-barrier).
// Register-safe by design: acc 64+8 f32 -> VGPR 88 (the 512-thread allocator cap
// of 128 VGPR makes every larger wave tile spill: R4/5/7/8/11).
// Co-residency alternatives all refuted: R12/R16 (1 blk/CU big-tile),
// R13/14 (BK=32 fixed-overhead), R17 (SPI won't admit 2nd block at VGPR>=132).
// LDS 160KB: sA dbuf 2x32KB @0, sB dbuf 2x16KB @65536, sH [256n][128h] 64KB @98304
__global__ __launch_bounds__(512)
__attribute__((amdgpu_waves_per_eu(2, 2)))
void fused_mlp(
    const bf16* __restrict__ XBF, const bf16* __restrict__ W1T,
    const bf16* __restrict__ W2T, const float* __restrict__ B1W,
    const float* __restrict__ B2W, const float* __restrict__ permu,
    float* __restrict__ out) {
  extern __shared__ char smem[];          // 163840 bytes

  int bid = blockIdx.x;
  // XCD swizzle: XCD x owns j in [8x,8x+8); each j's 4 n-tiles adjacent on one XCD
  int L = ((bid & 7) << 5) | (bid >> 3);
  int j = L >> 2;
  int n0 = (L & 3) << 8;

  int tid = threadIdx.x;
  int wid = tid >> 6;               // 0..7
  int lane = tid & 63;
  int l15 = lane & 15;
  int lg = lane >> 4;               // 0..3
  int wn = (wid >> 1) << 6;         // wave n offset (0,64,128,192)
  int wh = (wid & 1) << 6;          // wave h offset (0,64)
  int srow = tid >> 3;              // staging row 0..63 (+64 per q)
  int slot = tid & 7;               // staging 16B slot in 128B row

  const bf16* w1base = W1T + (size_t)j * (HD * XD);
  const bf16* w2g = W2T + (size_t)((j << 4) + l15) * HD;  // row y = l15
  bf16* sH = (bf16*)(smem + 98304);

  f32x4 acc2[2];
#pragma unroll
  for (int f = 0; f < 2; ++f)
#pragma unroll
    for (int r = 0; r < 4; ++r) acc2[f][r] = 0.0f;

  // stage into buf d: sA = x rows [n0, n0+256), sB = W1T rows [hb*128, +128)
  auto stage = [&](int d, int k0, int hb_) {
    char* aD = smem + d * 32768 + (tid << 4);
    char* bD = smem + 65536 + d * 16384 + (tid << 4);
#pragma unroll
    for (int q = 0; q < 4; ++q) {
      int r = (q << 6) + srow;
      int sc = slot ^ (r & 7);
      gload16(XBF + (size_t)(n0 + r) * XD + k0 + (sc << 3), aD + (q << 13));
      if (q < 2)
        gload16(w1base + (size_t)((hb_ << 7) + r) * XD + k0 + (sc << 3), bD + (q << 13));
    }
  };

  // prologue: stage (hb=0, t=0) into buf0
  stage(0, 0, 0);
  asm volatile("s_waitcnt vmcnt(0)" ::: "memory");
  __builtin_amdgcn_s_barrier();

#pragma unroll 1
  for (int hb = 0; hb < 8; ++hb) {
    // acc1[fb][fa]: fb = W1T(h) fragment, fa = x(n) fragment (swapped-operand MFMA)
    f32x4 acc1[4][4];
#pragma unroll
    for (int fb = 0; fb < 4; ++fb)
#pragma unroll
      for (int fa = 0; fa < 4; ++fa)
#pragma unroll
        for (int r = 0; r < 4; ++r) acc1[fb][fa][r] = 0.0f;

    int cur = 0;
#pragma unroll 1
    for (int t = 0; t < 8; ++t) {
      const char* a_d = smem + cur * 32768;
      const char* b_d = smem + 65536 + cur * 16384;
#pragma unroll
      for (int kk = 0; kk < 2; ++kk) {
        bf16x8 af[4], bg[4];
#pragma unroll
        for (int fa = 0; fa < 4; ++fa) {
          int ra = wn + (fa << 4) + l15;
          int ca = ((kk << 6) + (lg << 4)) ^ ((ra & 7) << 4);
          af[fa] = *(const bf16x8*)(a_d + (ra << 7) + ca);
        }
#pragma unroll
        for (int fb = 0; fb < 4; ++fb) {
          int rb = wh + (fb << 4) + l15;
          int cb = ((kk << 6) + (lg << 4)) ^ ((rb & 7) << 4);
          bg[fb] = *(const bf16x8*)(b_d + (rb << 7) + cb);
        }
        // stage issue AFTER the first frag-read burst, BEFORE the MFMA cluster:
        // reads own the LDS pipe right after the barrier; stage fills in behind.
        if (kk == 0) {
          if (t < 7)            stage(cur ^ 1, (t + 1) << 6, hb);
          else if (hb < 7)      stage(cur ^ 1, 0, hb + 1);
        }
        __builtin_amdgcn_s_setprio(1);
#pragma unroll
        for (int fb = 0; fb < 4; ++fb)
#pragma unroll
          for (int fa = 0; fa < 4; ++fa)
            acc1[fb][fa] = __builtin_amdgcn_mfma_f32_16x16x32_bf16(
                bg[fb], af[fa], acc1[fb][fa], 0, 0, 0);   // A=W1(h rows), B=x(n cols)
        __builtin_amdgcn_s_setprio(0);
      }
      asm volatile("s_waitcnt vmcnt(0)" ::: "memory");
      __builtin_amdgcn_s_barrier();
      cur ^= 1;
    }

    // W2 fragments for this hb (latency hidden under the sH-write phase)
    bf16x8 wg[4];
#pragma unroll
    for (int kk2 = 0; kk2 < 4; ++kk2)
      wg[kk2] = *(const bf16x8*)(w2g + (hb << 7) + (kk2 << 5) + (lg << 3));

    // ---- b1 + hardtanh -> sH [256 n][128 h], packed b64 writes
    // D layout: col(l15)=n-local, row(lg*4+r)=h-local -> r-consecutive = h-consecutive
    f32x4 b1v[4];
#pragma unroll
    for (int fb = 0; fb < 4; ++fb)
      b1v[fb] = *(const f32x4*)&B1W[(j << 10) + (hb << 7) + wh + (fb << 4) + (lg << 2)];
#pragma unroll
    for (int fa = 0; fa < 4; ++fa) {
#pragma unroll
      for (int fb = 0; fb < 4; ++fb) {
        bf16x4 pk;
#pragma unroll
        for (int r = 0; r < 4; ++r) {
          float v = acc1[fb][fa][r] + b1v[fb][r];
          v = fminf(1.0f, fmaxf(-1.0f, v));
          pk[r] = (bf16)v;
        }
        int n = wn + (fa << 4) + l15;
        int colb = (wh + (fb << 4) + (lg << 2)) << 1;       // byte col, 8B aligned
        int byte = (n << 8) + (colb ^ ((n & 7) << 4));
        *(bf16x4*)((char*)sH + byte) = pk;
      }
    }
    asm volatile("s_waitcnt lgkmcnt(0)" ::: "memory");  // sH writes retired
    __builtin_amdgcn_s_barrier();                       // sH visible to all waves
    // ---- GEMM2: wave owns rows wid*32..+32 of 256; W2 frags preloaded (wg)
#pragma unroll
    for (int kk2 = 0; kk2 < 4; ++kk2) {
#pragma unroll
      for (int f = 0; f < 2; ++f) {
        int row = (wid << 5) + (f << 4) + l15;
        int cb = ((kk2 << 6) + (lg << 4)) ^ ((row & 7) << 4);
        bf16x8 hf = *(const bf16x8*)((char*)sH + (row << 8) + cb);
        acc2[f] = __builtin_amdgcn_mfma_f32_16x16x32_bf16(hf, wg[kk2], acc2[f], 0, 0, 0);
      }
    }
    // no extra barrier: next sH write happens only after next hb's K-loop barriers
  }

  // ---- epilogue: b2, stage out tile (reuses sA region), permutation gather
  float b2v = B2W[(j << 4) + l15];
  float* sOut = (float*)smem;              // [256][17] f32 = 17408 B
  int* sIdx = (int*)(smem + 20480);        // [128]
#pragma unroll
  for (int f = 0; f < 2; ++f)
#pragma unroll
    for (int r = 0; r < 4; ++r) {
      int row = (wid << 5) + (f << 4) + (lg << 2) + r;
      sOut[row * 17 + l15] = acc2[f][r] + b2v;
    }
  if (tid < 128) {  // cidx[p][y] = c with permu[p][c][y]==1
    int p = tid >> 4, y = tid & 15;
    int c = 0;
#pragma unroll
    for (int cc = 0; cc < 16; ++cc)
      if (permu[((p << 4) + cc) * 16 + y] > 0.5f) c = cc;
    sIdx[tid] = c;
  }
  __syncthreads();
#pragma unroll 1
  for (int it = 0; it < 16; ++it) {
    int flat = (it << 11) + (tid << 2);   // p[3] n[8] y[4]
    int p = flat >> 12;
    int n = (flat >> 4) & 255;
    int y0 = flat & 15;
    f32x4 v;
#pragma unroll
    for (int q = 0; q < 4; ++q) v[q] = sOut[n * 17 + sIdx[(p << 4) + y0 + q]];
    *(f32x4*)(out + ((size_t)((j << 3) + p) * NN + n0 + n) * YD + y0) = v;
  }
}

extern "C" void kernel_launch(void* const* d_in, const int* in_sizes, int n_in,
                              void* d_out, int out_size, void* d_ws, size_t ws_size,
                              hipStream_t stream) {
  (void)in_sizes; (void)n_in; (void)out_size; (void)ws_size;
  const float* x      = (const float*)d_in[0];
  const float* mu_W1  = (const float*)d_in[1];
  const float* mu_b1  = (const float*)d_in[2];
  const float* mu_W2  = (const float*)d_in[3];
  const float* mu_b2  = (const float*)d_in[4];
  const float* sig_W1 = (const float*)d_in[5];
  const float* sig_b1 = (const float*)d_in[6];
  const float* sig_W2 = (const float*)d_in[7];
  const float* sig_b2 = (const float*)d_in[8];
  const float* e_W1   = (const float*)d_in[9];
  const float* e_b1   = (const float*)d_in[10];
  const float* e_W2   = (const float*)d_in[11];
  const float* e_b2   = (const float*)d_in[12];
  const float* permu  = (const float*)d_in[13];
  float* out = (float*)d_out;

  char* ws = (char*)d_ws;
  bf16* W1T = (bf16*)(ws);
  bf16* W2T = (bf16*)(ws + 67108864);
  bf16* XBF = (bf16*)(ws + 69206016);
  float* B1W = (float*)(ws + 70254592);
  float* B2W = (float*)(ws + 70516736);

  static int lds_set = 0;
  if (!lds_set) {  // idempotent host-side attribute; not a stream op (capture-safe)
    hipFuncSetAttribute((const void*)fused_mlp,
                        hipFuncAttributeMaxDynamicSharedMemorySize, 163840);
    lds_set = 1;
  }

  build_all<<<dim3(14596), dim3(256), 0, stream>>>(
      mu_W1, sig_W1, e_W1, W1T,
      x, mu_W2, sig_W2, e_W2, mu_b1, sig_b1, e_b1, mu_b2, sig_b2, e_b2,
      XBF, W2T, B1W, B2W);
  fused_mlp<<<dim3(256), dim3(512), 163840, stream>>>(
      XBF, W1T, W2T, B1W, B2W, permu, out);
}